// Round 1
// 1315.051 us; speedup vs baseline: 1.0635x; 1.0635x over previous
//
#include <hip/hip_runtime.h>
#include <stdint.h>

#define Hn 512
#define Dn 128
#define Nn 64
#define Tn 512
#define NT (Nn*Tn)   // 32768

typedef unsigned int uint;
typedef unsigned short ushort;
typedef unsigned long long u64;

typedef __attribute__((ext_vector_type(4))) float f32x4;

// ---------- ws layout (bytes) ----------
// emitb : 0x0000000  NT*Hn*2  = 32 MB   (exp(emit-rowmax), bf16)
// rm    : 0x2000000  NT*4     = 128 KB
// wmat  : 0x2020000  Hn*Dn*4  = 256 KB
// bias  : 0x2060000  Hn*4     = 2 KB
// cs    : 0x2061000  Hn*4     (448/colmax of P)
// rcsg  : 0x2062000  Hn*4     (colmax/448)
// pq    : 0x2070000  16*32*64*8 = 256 KB (P fp8 e4m3, MFMA B-frag order [kt 0..15][nt 0..31][lane])

__device__ inline float bf2f(ushort u) { union { uint i; float f; } v; v.i = uint(u) << 16; return v.f; }
__device__ inline ushort f2bf(float f) {
  union { uint i; float f; } v; v.f = f;
  uint u = v.i;
  uint r = (u + 0x7FFFu + ((u >> 16) & 1u)) >> 16;
  return ushort(r);
}
// e4m3fn decode (non-negative only); used in finale only
__device__ inline float fp8val(uint b) {
  uint e = (b >> 3) & 15u, m = b & 7u;
  return e ? ldexpf((float)(8u + m), (int)e - 10) : ldexpf((float)m, -9);
}
// pack 8 floats (k-ascending) to 8 e4m3 bytes; SAME helper packs A and B frags,
// so any HW k-permutation within the 32-k tile cancels between operands.
__device__ inline u64 pack8fp8(const float* v, float qs) {
  int lo = 0, hi = 0;
  lo = __builtin_amdgcn_cvt_pk_fp8_f32(v[0] * qs, v[1] * qs, lo, false);
  lo = __builtin_amdgcn_cvt_pk_fp8_f32(v[2] * qs, v[3] * qs, lo, true);
  hi = __builtin_amdgcn_cvt_pk_fp8_f32(v[4] * qs, v[5] * qs, hi, false);
  hi = __builtin_amdgcn_cvt_pk_fp8_f32(v[6] * qs, v[7] * qs, hi, true);
  return (u64)(uint)lo | ((u64)(uint)hi << 32);
}

__global__ void k_prep(const float* __restrict__ py, float* __restrict__ wmat, float* __restrict__ bias) {
  int h = blockIdx.x, d = threadIdx.x;
  float p = py[h * Dn + d];
  float lp = logf(p), l1 = log1pf(-p);
  wmat[h * Dn + d] = lp - l1;
  float v = l1;
  for (int o = 1; o < 64; o <<= 1) v += __shfl_xor(v, o, 64);
  __shared__ float s2[2];
  if ((threadIdx.x & 63) == 0) s2[threadIdx.x >> 6] = v;
  __syncthreads();
  if (threadIdx.x == 0) bias[h] = s2[0] + s2[1];
}

// per-column max of P -> cs = 448/max, rcsg = max/448
__global__ void k_cs(const float* __restrict__ px, float* __restrict__ cs, float* __restrict__ rcsg) {
  int j = threadIdx.x;  // 512 threads
  float m = 0.f;
#pragma unroll 8
  for (int k = 0; k < Hn; k++) m = fmaxf(m, px[(size_t)k * Hn + j]);
  cs[j] = 448.0f / m;
  rcsg[j] = m * (1.0f / 448.0f);
}

// quantize P (col-scaled) into MFMA B-frag order: pq[(kt*32 + nt)*64 + lane] (8 bytes k-ascending)
__global__ __launch_bounds__(256) void k_pq(const float* __restrict__ px, const float* __restrict__ cs,
                                            u64* __restrict__ pq) {
  __shared__ float ksl[32][260];
  int g = blockIdx.x & 1, kt = blockIdx.x >> 1;  // kt = global k-tile 0..15
  int t = threadIdx.x;
  int k0 = kt * 32;
  for (int i = 0; i < 8; i++) {
    int q = i * 256 + t;          // float4 id over 32x64
    int row = q >> 6, c4 = q & 63;
    float4 v = *(const float4*)(px + (size_t)(k0 + row) * Hn + g * 256 + c4 * 4);
    ksl[row][c4 * 4 + 0] = v.x; ksl[row][c4 * 4 + 1] = v.y;
    ksl[row][c4 * 4 + 2] = v.z; ksl[row][c4 * 4 + 3] = v.w;
  }
  __syncthreads();
  for (int i = 0; i < 4; i++) {
    int fid = i * 256 + t;        // (ntl, lane)
    int ntl = fid >> 6, l = fid & 63;
    int col = ntl * 16 + (l & 15);
    int kr0 = (l >> 4) * 8;
    float csv = cs[g * 256 + col];
    float vv[8];
#pragma unroll
    for (int j = 0; j < 8; j++) vv[j] = ksl[kr0 + j][col];
    pq[(size_t)((kt * 32 + g * 16 + ntl) * 64 + l)] = pack8fp8(vv, csv);
  }
}

__global__ __launch_bounds__(256) void k_emit(const float* __restrict__ A, const float* __restrict__ wmat,
                                              const float* __restrict__ bias, ushort* __restrict__ eb) {
  __shared__ float As[Dn][64];
  __shared__ float Bs[Dn][64];
  int t = threadIdx.x;
  int r0 = blockIdx.y * 64, h0 = blockIdx.x * 64;
  int row = t >> 2, q = t & 3;
  for (int i = 0; i < 8; i++) {
    int ch = q + i * 4;
    float4 a = *(const float4*)(A + (size_t)(r0 + row) * Dn + ch * 4);
    As[ch * 4 + 0][row] = a.x; As[ch * 4 + 1][row] = a.y;
    As[ch * 4 + 2][row] = a.z; As[ch * 4 + 3][row] = a.w;
    float4 b = *(const float4*)(wmat + (size_t)(h0 + row) * Dn + ch * 4);
    Bs[ch * 4 + 0][row] = b.x; Bs[ch * 4 + 1][row] = b.y;
    Bs[ch * 4 + 2][row] = b.z; Bs[ch * 4 + 3][row] = b.w;
  }
  __syncthreads();
  int tx = t & 15, ty = t >> 4;
  float acc[4][4] = {};
  for (int k = 0; k < Dn; k++) {
    float av[4], bv[4];
    *(float4*)av = *(const float4*)&As[k][ty * 4];
    *(float4*)bv = *(const float4*)&Bs[k][tx * 4];
#pragma unroll
    for (int ii = 0; ii < 4; ii++)
#pragma unroll
      for (int jj = 0; jj < 4; jj++) acc[ii][jj] += av[ii] * bv[jj];
  }
  float bsv[4];
  *(float4*)bsv = *(const float4*)(bias + h0 + tx * 4);
#pragma unroll
  for (int ii = 0; ii < 4; ii++) {
    int r = r0 + ty * 4 + ii;
    ushort4 u;
    u.x = f2bf(acc[ii][0] + bsv[0]); u.y = f2bf(acc[ii][1] + bsv[1]);
    u.z = f2bf(acc[ii][2] + bsv[2]); u.w = f2bf(acc[ii][3] + bsv[3]);
    *(ushort4*)(eb + (size_t)r * Hn + h0 + tx * 4) = u;
  }
}

__global__ void k_rowmax(const ushort* __restrict__ eb, float* __restrict__ rm) {
  int r = blockIdx.x, lane = threadIdx.x;
  uint4 u = *(const uint4*)(eb + (size_t)r * Hn + lane * 8);
  float m = bf2f(ushort(u.x & 0xffff));
  m = fmaxf(m, bf2f(ushort(u.x >> 16)));
  m = fmaxf(m, bf2f(ushort(u.y & 0xffff))); m = fmaxf(m, bf2f(ushort(u.y >> 16)));
  m = fmaxf(m, bf2f(ushort(u.z & 0xffff))); m = fmaxf(m, bf2f(ushort(u.z >> 16)));
  m = fmaxf(m, bf2f(ushort(u.w & 0xffff))); m = fmaxf(m, bf2f(ushort(u.w >> 16)));
  for (int o = 1; o < 64; o <<= 1) m = fmaxf(m, __shfl_xor(m, o, 64));
  if (lane == 0) rm[r] = m;
}

__global__ void k_bexp(ushort* __restrict__ eb, const float* __restrict__ rm) {
  int i = blockIdx.x * 256 + threadIdx.x;
  uint* p = (uint*)eb;
  uint u = p[i];
  float m = rm[i >> 8];
  float f0 = expf(bf2f(ushort(u & 0xffff)) - m);
  float f1 = expf(bf2f(ushort(u >> 16)) - m);
  p[i] = uint(f2bf(f0)) | (uint(f2bf(f1)) << 16);
}

// 4 WGs = 4 seq-groups of 16 seqs each; 512 threads; full 512-col recursion per WG.
// P fp8 B-frags live ENTIRELY in registers (128 VGPR/lane) -> no inter-WG exchange,
// no mailbox, no cross-XCD poll. Alpha frags cycle through LDS only.
__global__ __launch_bounds__(512) void k_rec3(
    const ushort* __restrict__ eb, const float* __restrict__ rm,
    const u64* __restrict__ pq, const float* __restrict__ px,
    const float* __restrict__ rcsg, const int* __restrict__ lens,
    float* __restrict__ outp) {
  const int grp = blockIdx.x;        // 0..3
  const int t = threadIdx.x;         // 0..511
  const int w = t >> 6, lane = t & 63, quad = (t >> 4) & 3, l15 = t & 15;

  __shared__ float ut[16][516];      // u values, fp32 (stride 516 breaks bank patterns)
  __shared__ u64 AfL[16 * 64];       // alpha A-frags [kt 0..15][lane]
  __shared__ float rcsL[512];
  __shared__ float moS[16], rqsS[16], CaccS[16];
  __shared__ float sred[8][16];
  __shared__ int lenl[16];

  // ---- persistent P fragments: wave w owns n-tiles w*4 .. w*4+3 ----
  u64 PR[64];
#pragma unroll
  for (int kt = 0; kt < 16; kt++)
#pragma unroll
    for (int i = 0; i < 4; i++)
      PR[kt * 4 + i] = pq[(size_t)((kt * 32 + w * 4 + i) * 64 + lane)];

  rcsL[t] = rcsg[t];
  if (t < 16) {
    lenl[t] = lens[grp * 16 + t];
    CaccS[t] = rm[(size_t)(grp * 16 + t) * Tn];
  }

  // ---- init: v0[s][j] = px[0][j] * eb[s][0][j] ----
  {
    int s = t >> 5, c0 = (t & 31) * 16;
    const float* pxr = px + c0;
    const ushort* er = eb + (size_t)(grp * 16 + s) * Tn * Hn + c0;
#pragma unroll
    for (int m = 0; m < 16; m += 4) {
      float4 p = *(const float4*)(pxr + m);
      ut[s][c0 + m + 0] = p.x * bf2f(er[m + 0]);
      ut[s][c0 + m + 1] = p.y * bf2f(er[m + 1]);
      ut[s][c0 + m + 2] = p.z * bf2f(er[m + 2]);
      ut[s][c0 + m + 3] = p.w * bf2f(er[m + 3]);
    }
  }
  __syncthreads();
  // init max-reduce
  {
    int s = t >> 5, ch = t & 31;
    float m = 0.f;
#pragma unroll
    for (int p = 0; p < 4; p++) {
      float4 x = *(float4*)&ut[s][p * 128 + ch * 4];
      m = fmaxf(m, fmaxf(fmaxf(x.x, x.y), fmaxf(x.z, x.w)));
    }
    for (int o = 1; o <= 16; o <<= 1) m = fmaxf(m, __shfl_xor(m, o, 64));
    if (ch == 0) {
      rqsS[s] = 448.0f * __builtin_amdgcn_rcpf(m);
      moS[s] = m * (1.0f / 448.0f);
    }
  }
  __syncthreads();
  const int t_end = lenl[15];
  // quantize step 0 (all seqs active)
  {
    int s2 = l15;
    float qs = rqsS[s2];
#pragma unroll
    for (int hf = 0; hf < 2; hf++) {
      int kt = w + hf * 8, k0 = kt * 32 + quad * 8;
      float vv[8];
#pragma unroll
      for (int j = 0; j < 8; j++) vv[j] = ut[s2][k0 + j];
      AfL[kt * 64 + lane] = pack8fp8(vv, qs);
    }
  }
  // prefetch emit slice + rm for ts=1
  ushort bp0[4], bp1[4], bp2[4], bp3[4];
  float rmpre = 0.f;
  {
#pragma unroll
    for (int r = 0; r < 4; r++) {
      const ushort* ebp = eb + ((size_t)(grp * 16 + quad * 4 + r) * Tn + 1) * Hn + w * 64 + l15;
      bp0[r] = ebp[0]; bp1[r] = ebp[16]; bp2[r] = ebp[32]; bp3[r] = ebp[48];
    }
    if (t < 16) rmpre = rm[(size_t)(grp * 16 + t) * Tn + 1];
  }

  // ---- recursion: 3 intra-WG barriers per step, zero global traffic on critical path ----
  for (int ts = 1; ts < t_end; ts++) {
    __syncthreads();  // B0: AfL ready, ut free for overwrite
    // prefetch ts+1 NOW so the vmcnt drain at B2 lands after the MFMA phase
    ushort bq0[4], bq1[4], bq2[4], bq3[4];
    float rmpreN = 0.f;
    {
      int tsn = (ts + 1 < Tn) ? ts + 1 : Tn - 1;
#pragma unroll
      for (int r = 0; r < 4; r++) {
        const ushort* ebp = eb + ((size_t)(grp * 16 + quad * 4 + r) * Tn + tsn) * Hn + w * 64 + l15;
        bq0[r] = ebp[0]; bq1[r] = ebp[16]; bq2[r] = ebp[32]; bq3[r] = ebp[48];
      }
      if (t < 16) rmpreN = rm[(size_t)(grp * 16 + t) * Tn + tsn];
    }
    // MFMA: 16 k-tiles x 4 n-tiles, B operands from registers
    f32x4 ac0 = {0.f, 0.f, 0.f, 0.f}, ac1 = {0.f, 0.f, 0.f, 0.f};
    f32x4 ac2 = {0.f, 0.f, 0.f, 0.f}, ac3 = {0.f, 0.f, 0.f, 0.f};
#pragma unroll
    for (int kt = 0; kt < 16; kt++) {
      u64 af = AfL[kt * 64 + lane];
      ac0 = __builtin_amdgcn_mfma_f32_16x16x32_fp8_fp8((long)af, (long)PR[kt * 4 + 0], ac0, 0, 0, 0);
      ac1 = __builtin_amdgcn_mfma_f32_16x16x32_fp8_fp8((long)af, (long)PR[kt * 4 + 1], ac1, 0, 0, 0);
      ac2 = __builtin_amdgcn_mfma_f32_16x16x32_fp8_fp8((long)af, (long)PR[kt * 4 + 2], ac2, 0, 0, 0);
      ac3 = __builtin_amdgcn_mfma_f32_16x16x32_fp8_fp8((long)af, (long)PR[kt * 4 + 3], ac3, 0, 0, 0);
    }
    // running log-normalizer: uses PRE-update moS (scale of the frags just consumed)
    if (t < 16 && ts < lenl[t]) CaccS[t] += logf(moS[t]) + rmpre;
    // epilogue: u = acc * (colmax/448) * emit   (alpha scale folded into Cacc)
    {
      int jb = w * 64 + l15;
      float rc0 = rcsL[jb], rc1 = rcsL[jb + 16], rc2 = rcsL[jb + 32], rc3 = rcsL[jb + 48];
#pragma unroll
      for (int r = 0; r < 4; r++) {
        int s = quad * 4 + r;
        ut[s][jb + 0]  = ac0[r] * rc0 * bf2f(bp0[r]);
        ut[s][jb + 16] = ac1[r] * rc1 * bf2f(bp1[r]);
        ut[s][jb + 32] = ac2[r] * rc2 * bf2f(bp2[r]);
        ut[s][jb + 48] = ac3[r] * rc3 * bf2f(bp3[r]);
      }
    }
    __syncthreads();  // B2: ut complete (prefetch loads drained here, already landed)
    // per-seq max over 512 cols; update scales for active seqs
    {
      int s = t >> 5, ch = t & 31;
      float m = 0.f;
#pragma unroll
      for (int p = 0; p < 4; p++) {
        float4 x = *(float4*)&ut[s][p * 128 + ch * 4];
        m = fmaxf(m, fmaxf(fmaxf(x.x, x.y), fmaxf(x.z, x.w)));
      }
      for (int o = 1; o <= 16; o <<= 1) m = fmaxf(m, __shfl_xor(m, o, 64));
      if (ch == 0) {
        rqsS[s] = 448.0f * __builtin_amdgcn_rcpf(m);
        if (ts < lenl[s]) moS[s] = m * (1.0f / 448.0f);
      }
    }
    __syncthreads();  // B3: scales ready
    // quantize (frozen seqs keep old frags)
    {
      int s2 = l15;
      if (ts < lenl[s2]) {
        float qs = rqsS[s2];
#pragma unroll
        for (int hf = 0; hf < 2; hf++) {
          int kt = w + hf * 8, k0 = kt * 32 + quad * 8;
          float vv[8];
#pragma unroll
          for (int j = 0; j < 8; j++) vv[j] = ut[s2][k0 + j];
          AfL[kt * 64 + lane] = pack8fp8(vv, qs);
        }
      }
    }
    // rotate prefetch registers
#pragma unroll
    for (int r = 0; r < 4; r++) {
      bp0[r] = bq0[r]; bp1[r] = bq1[r]; bp2[r] = bq2[r]; bp3[r] = bq3[r];
    }
    rmpre = rmpreN;
  }

  // ---- finale: sum dequantized final frags per seq ----
  __syncthreads();
  {
    u64 v0 = AfL[w * 64 + lane], v1 = AfL[(w + 8) * 64 + lane];
    float p = 0.f;
#pragma unroll
    for (int j = 0; j < 8; j++) {
      p += fp8val((uint)(v0 >> (8 * j)) & 0xffu);
      p += fp8val((uint)(v1 >> (8 * j)) & 0xffu);
    }
    p += __shfl_xor(p, 16, 64);
    p += __shfl_xor(p, 32, 64);
    if (lane < 16) sred[w][lane] = p;
  }
  __syncthreads();
  if (t < 16) {
    float S = 0.f;
#pragma unroll
    for (int ww = 0; ww < 8; ww++) S += sred[ww][t];
    outp[grp * 16 + t] = CaccS[t] + logf(moS[t] * S);
  }
}

extern "C" void kernel_launch(void* const* d_in, const int* in_sizes, int n_in,
                              void* d_out, int out_size, void* d_ws, size_t ws_size,
                              hipStream_t stream) {
  const float* seq = (const float*)d_in[0];
  const int* lens = (const int*)d_in[1];
  const float* px = (const float*)d_in[2];
  const float* py = (const float*)d_in[3];
  char* ws = (char*)d_ws;
  ushort* emitb = (ushort*)(ws + 0x0000000);
  float* rm     = (float*)(ws + 0x2000000);
  float* wmat   = (float*)(ws + 0x2020000);
  float* bias   = (float*)(ws + 0x2060000);
  float* cs     = (float*)(ws + 0x2061000);
  float* rcsg   = (float*)(ws + 0x2062000);
  u64* pq       = (u64*)(ws + 0x2070000);
  float* outp   = (float*)d_out;

  hipLaunchKernelGGL(k_prep, dim3(512), dim3(128), 0, stream, py, wmat, bias);
  hipLaunchKernelGGL(k_cs, dim3(1), dim3(512), 0, stream, px, cs, rcsg);
  hipLaunchKernelGGL(k_pq, dim3(32), dim3(256), 0, stream, px, cs, pq);
  hipLaunchKernelGGL(k_emit, dim3(8, 512), dim3(256), 0, stream, seq, wmat, bias, emitb);
  hipLaunchKernelGGL(k_rowmax, dim3(NT), dim3(64), 0, stream, emitb, rm);
  hipLaunchKernelGGL(k_bexp, dim3(NT), dim3(256), 0, stream, emitb, rm);
  hipLaunchKernelGGL(k_rec3, dim3(4), dim3(512), 0, stream, emitb, rm, pq, px, rcsg, lens, outp);
}